// Round 1
// baseline (1048.362 us; speedup 1.0000x reference)
//
#include <hip/hip_runtime.h>

// ---------------------------------------------------------------------------
// HierarchicalCellEncoder — fused fp32 baseline.
//
// Algebra (all exact):
//   emb0  = X @ Wf + bf                 Wf = W0@Wout, bf = b0@Wout + bout
//   A1    = masked_mean(X,    d1_chunk_idx, d1_chunk_mask)
//   B1    = masked_mean(emb0, d1_bnd_idx,   d1_bnd_mask)
//   h1    = A1@U1 + B1@W1a_bot + c1     U1 = W0@W1a_top, c1 = b0@W1a_top + b1a
//   emb1  = relu(h1) @ V1 + d1c         V1 = W1b@Wout,  d1c = b1b@Wout + bout
//   (dim 2 identical with W2a/W2b, K2=32, B2=8, source emb1)
// ---------------------------------------------------------------------------

#define DD 256

// out[j] = add[j] + sum_k b[k] * R[k*256 + j]      (one block of 256 threads)
__global__ void bias_fuse(const float* __restrict__ b, const float* __restrict__ R,
                          const float* __restrict__ add, float* __restrict__ out) {
    int j = threadIdx.x;
    float s = add[j];
    for (int k = 0; k < DD; ++k) s += b[k] * R[k * DD + j];
    out[j] = s;
}

// masked mean gather: out[c,:] = where(cnt>0, sum_k m*src[idx[c,k],:]/max(cnt,1), 0)
// blockDim = (64,4): 64 lanes x float4 cover D=256; 4 cells per block.
__global__ __launch_bounds__(256) void gather_mean(
    const float* __restrict__ src, const int* __restrict__ idx,
    const float* __restrict__ mask, float* __restrict__ out, int C, int K) {
    int c = blockIdx.x * 4 + threadIdx.y;
    if (c >= C) return;
    int t = threadIdx.x;  // 0..63
    float4 acc = {0.f, 0.f, 0.f, 0.f};
    float cnt = 0.f;
    for (int k = 0; k < K; ++k) {
        float m = mask[(size_t)c * K + k];
        cnt += m;
        if (m != 0.f) {
            int r = idx[(size_t)c * K + k];
            float4 v = *(const float4*)&src[(size_t)r * DD + t * 4];
            acc.x += m * v.x; acc.y += m * v.y; acc.z += m * v.z; acc.w += m * v.w;
        }
    }
    float inv = (cnt > 0.f) ? 1.f / fmaxf(cnt, 1.f) : 0.f;
    acc.x *= inv; acc.y *= inv; acc.z *= inv; acc.w *= inv;
    *(float4*)&out[(size_t)c * DD + t * 4] = acc;
}

// C[M,256] = act(A0)@W0p (+ act(A1p)@W1p) + bias.
// Tile: BM=BN=64, BK=16, 256 threads, 4x4 micro-tile per thread.
// As stored transposed [k][m] (pad 68: write 2-way conflict = free, read broadcast).
template<int RELU_IN, int TWO>
__global__ __launch_bounds__(256) void gemm_k256(
    const float* __restrict__ A0, const float* __restrict__ A1p,
    const float* __restrict__ W0p, const float* __restrict__ W1p,
    const float* __restrict__ bias, float* __restrict__ Cp, int M) {
    __shared__ float As[16][68];
    __shared__ float Bs[16][68];
    const int tid = threadIdx.x;
    const int bm = blockIdx.x * 64;
    const int bn = blockIdx.y * 64;
    const int tx = tid & 15;   // output col group
    const int ty = tid >> 4;   // output row group
    const int lm  = tid >> 2;         // A-load row 0..63
    const int lk4 = (tid & 3) * 4;    // A-load k quad
    const int wk  = tid >> 4;         // W-load k 0..15
    const int wn  = (tid & 15) * 4;   // W-load col quad

    float acc[4][4] = {};

    const int nparts = TWO ? 2 : 1;
    for (int part = 0; part < nparts; ++part) {
        const float* __restrict__ A = part ? A1p : A0;
        const float* __restrict__ W = part ? W1p : W0p;
        for (int k0 = 0; k0 < DD; k0 += 16) {
            float4 av = {0.f, 0.f, 0.f, 0.f};
            int arow = bm + lm;
            if (arow < M) av = *(const float4*)&A[(size_t)arow * DD + k0 + lk4];
            if (RELU_IN) {
                av.x = fmaxf(av.x, 0.f); av.y = fmaxf(av.y, 0.f);
                av.z = fmaxf(av.z, 0.f); av.w = fmaxf(av.w, 0.f);
            }
            float4 wv = *(const float4*)&W[(size_t)(k0 + wk) * DD + bn + wn];
            __syncthreads();   // protect previous iteration's LDS reads
            As[lk4 + 0][lm] = av.x;
            As[lk4 + 1][lm] = av.y;
            As[lk4 + 2][lm] = av.z;
            As[lk4 + 3][lm] = av.w;
            *(float4*)&Bs[wk][wn] = wv;
            __syncthreads();
#pragma unroll
            for (int k = 0; k < 16; ++k) {
                float4 a = *(const float4*)&As[k][ty * 4];
                float4 b = *(const float4*)&Bs[k][tx * 4];
                float ar[4] = {a.x, a.y, a.z, a.w};
                float br[4] = {b.x, b.y, b.z, b.w};
#pragma unroll
                for (int i = 0; i < 4; ++i)
#pragma unroll
                    for (int j = 0; j < 4; ++j)
                        acc[i][j] = fmaf(ar[i], br[j], acc[i][j]);
            }
        }
    }

    float4 bv = {0.f, 0.f, 0.f, 0.f};
    if (bias) bv = *(const float4*)&bias[bn + tx * 4];
#pragma unroll
    for (int i = 0; i < 4; ++i) {
        int row = bm + ty * 4 + i;
        if (row < M) {
            float4 o;
            o.x = acc[i][0] + bv.x;
            o.y = acc[i][1] + bv.y;
            o.z = acc[i][2] + bv.z;
            o.w = acc[i][3] + bv.w;
            *(float4*)&Cp[(size_t)row * DD + bn + tx * 4] = o;
        }
    }
}

extern "C" void kernel_launch(void* const* d_in, const int* in_sizes, int n_in,
                              void* d_out, int out_size, void* d_ws, size_t ws_size,
                              hipStream_t stream) {
    const float* X     = (const float*)d_in[0];
    const int*   d1_ci = (const int*)d_in[1];
    const int*   d1_bi = (const int*)d_in[2];
    const int*   d2_ci = (const int*)d_in[3];
    const int*   d2_bi = (const int*)d_in[4];
    const float* d1_cm = (const float*)d_in[5];
    const float* d1_bm = (const float*)d_in[6];
    const float* d2_cm = (const float*)d_in[7];
    const float* d2_bm = (const float*)d_in[8];
    const float* W0   = (const float*)d_in[9];
    const float* b0   = (const float*)d_in[10];
    const float* W1a  = (const float*)d_in[11];
    const float* b1a  = (const float*)d_in[12];
    const float* W1b  = (const float*)d_in[13];
    const float* b1b  = (const float*)d_in[14];
    const float* W2a  = (const float*)d_in[15];
    const float* b2a  = (const float*)d_in[16];
    const float* W2b  = (const float*)d_in[17];
    const float* b2b  = (const float*)d_in[18];
    const float* Wout = (const float*)d_in[19];
    const float* bout = (const float*)d_in[20];

    const int N  = in_sizes[0] / DD;   // 100000
    const int C1 = in_sizes[1] / 16;   // 50000
    const int C2 = in_sizes[3] / 32;   // 10000
    const int K1 = 16, K2 = 32, KB2 = 8;

    float* out  = (float*)d_out;
    float* emb0 = out;
    float* emb1 = out + (size_t)N * DD;
    float* emb2 = out + (size_t)(N + C1) * DD;

    // workspace layout (floats). Peak ~155 MB.
    float* ws = (float*)d_ws;
    float* A1  = ws;                            // [C1,256]
    float* B1  = ws + (size_t)C1 * DD;          // [C1,256]
    float* H1  = ws + (size_t)2 * C1 * DD;      // [C1,256]
    float* A2  = ws;                            // reuse (A1 dead after h1)
    float* B2m = ws + (size_t)C2 * DD;
    float* H2  = ws + (size_t)2 * C2 * DD;
    float* WF  = ws + (size_t)3 * C1 * DD;      // 5 fused 256x256 weights
    float* Wf  = WF + 0 * 65536;
    float* U1  = WF + 1 * 65536;
    float* V1  = WF + 2 * 65536;
    float* U2  = WF + 3 * 65536;
    float* V2  = WF + 4 * 65536;
    float* BF  = WF + 5 * 65536;                // 5 fused bias vectors
    const float* W1a_bot = W1a + 65536;         // rows 256..511
    const float* W2a_bot = W2a + 65536;

    dim3 tb(256);
    dim3 gW(4, 4);  // 256x256 outputs

    // --- fuse weights (tiny GEMMs) ---
    gemm_k256<0, 0><<<gW, tb, 0, stream>>>(W0,  nullptr, Wout, nullptr, nullptr, Wf, 256);
    gemm_k256<0, 0><<<gW, tb, 0, stream>>>(W0,  nullptr, W1a,  nullptr, nullptr, U1, 256);
    gemm_k256<0, 0><<<gW, tb, 0, stream>>>(W1b, nullptr, Wout, nullptr, nullptr, V1, 256);
    gemm_k256<0, 0><<<gW, tb, 0, stream>>>(W0,  nullptr, W2a,  nullptr, nullptr, U2, 256);
    gemm_k256<0, 0><<<gW, tb, 0, stream>>>(W2b, nullptr, Wout, nullptr, nullptr, V2, 256);
    // --- fuse biases ---
    bias_fuse<<<1, 256, 0, stream>>>(b0,  Wout, bout, BF + 0);     // bf
    bias_fuse<<<1, 256, 0, stream>>>(b0,  W1a,  b1a,  BF + 256);   // c1
    bias_fuse<<<1, 256, 0, stream>>>(b1b, Wout, bout, BF + 512);   // d1c
    bias_fuse<<<1, 256, 0, stream>>>(b0,  W2a,  b2a,  BF + 768);   // c2
    bias_fuse<<<1, 256, 0, stream>>>(b2b, Wout, bout, BF + 1024);  // d2c

    // --- dim 0: emb0 = X @ Wf + bf ---
    gemm_k256<0, 0><<<dim3((N + 63) / 64, 4), tb, 0, stream>>>(
        X, nullptr, Wf, nullptr, BF + 0, emb0, N);

    // --- dim 1 ---
    gather_mean<<<dim3((C1 + 3) / 4), dim3(64, 4), 0, stream>>>(X,    d1_ci, d1_cm, A1, C1, K1);
    gather_mean<<<dim3((C1 + 3) / 4), dim3(64, 4), 0, stream>>>(emb0, d1_bi, d1_bm, B1, C1, K1);
    gemm_k256<0, 1><<<dim3((C1 + 63) / 64, 4), tb, 0, stream>>>(
        A1, B1, U1, W1a_bot, BF + 256, H1, C1);
    gemm_k256<1, 0><<<dim3((C1 + 63) / 64, 4), tb, 0, stream>>>(
        H1, nullptr, V1, nullptr, BF + 512, emb1, C1);

    // --- dim 2 ---
    gather_mean<<<dim3((C2 + 3) / 4), dim3(64, 4), 0, stream>>>(X,    d2_ci, d2_cm, A2, C2, K2);
    gather_mean<<<dim3((C2 + 3) / 4), dim3(64, 4), 0, stream>>>(emb1, d2_bi, d2_bm, B2m, C2, KB2);
    gemm_k256<0, 1><<<dim3((C2 + 63) / 64, 4), tb, 0, stream>>>(
        A2, B2m, U2, W2a_bot, BF + 768, H2, C2);
    gemm_k256<1, 0><<<dim3((C2 + 63) / 64, 4), tb, 0, stream>>>(
        H2, nullptr, V2, nullptr, BF + 1024, emb2, C2);
}

// Round 2
// 500.976 us; speedup vs baseline: 2.0926x; 2.0926x over previous
//
#include <hip/hip_runtime.h>
#include <cstdint>

typedef unsigned short u16;
typedef unsigned int u32;
typedef __attribute__((ext_vector_type(8))) short bf16x8;
typedef __attribute__((ext_vector_type(4))) float f32x4;

#define DD 256

__device__ __forceinline__ u16 f2bf(float f) {
    u32 u = __float_as_uint(f);
    u32 r = (u + 0x7FFFu + ((u >> 16) & 1u)) >> 16;
    return (u16)r;
}
__device__ __forceinline__ float bf2f(u16 v) {
    return __uint_as_float(((u32)v) << 16);
}

// ---------------------------------------------------------------------------
// fp32 64x64-tile GEMM core (K=256, M=256) — used only for tiny weight fusion
// ---------------------------------------------------------------------------
__device__ __forceinline__ void gemm64_f32(const float* __restrict__ A,
                                           const float* __restrict__ W,
                                           float* __restrict__ C, int bm, int bn) {
    __shared__ float As[16][68];
    __shared__ float Bs[16][68];
    const int tid = threadIdx.x;
    const int tx = tid & 15, ty = tid >> 4;
    const int lm = tid >> 2, lk4 = (tid & 3) * 4;
    const int wk = tid >> 4, wn = (tid & 15) * 4;
    float acc[4][4] = {};
    for (int k0 = 0; k0 < DD; k0 += 16) {
        float4 av = *(const float4*)&A[(size_t)(bm + lm) * DD + k0 + lk4];
        float4 wv = *(const float4*)&W[(size_t)(k0 + wk) * DD + bn + wn];
        __syncthreads();
        As[lk4 + 0][lm] = av.x; As[lk4 + 1][lm] = av.y;
        As[lk4 + 2][lm] = av.z; As[lk4 + 3][lm] = av.w;
        *(float4*)&Bs[wk][wn] = wv;
        __syncthreads();
#pragma unroll
        for (int k = 0; k < 16; ++k) {
            float4 a = *(const float4*)&As[k][ty * 4];
            float4 b = *(const float4*)&Bs[k][tx * 4];
            float ar[4] = {a.x, a.y, a.z, a.w};
            float br[4] = {b.x, b.y, b.z, b.w};
#pragma unroll
            for (int i = 0; i < 4; ++i)
#pragma unroll
                for (int j = 0; j < 4; ++j)
                    acc[i][j] = fmaf(ar[i], br[j], acc[i][j]);
        }
    }
#pragma unroll
    for (int i = 0; i < 4; ++i) {
        float4 o = {acc[i][0], acc[i][1], acc[i][2], acc[i][3]};
        *(float4*)&C[(size_t)(bm + ty * 4 + i) * DD + bn + tx * 4] = o;
    }
}

// 5 fused 256x256 fp32 weights in one launch: Wf,U1,V1,U2,V2
__global__ __launch_bounds__(256) void fuse_weights(
    const float* __restrict__ W0, const float* __restrict__ W1a,
    const float* __restrict__ W1b, const float* __restrict__ W2a,
    const float* __restrict__ W2b, const float* __restrict__ Wout,
    float* __restrict__ dst) {
    const float *P, *Q;
    switch (blockIdx.z) {
        case 0: P = W0;  Q = Wout; break;
        case 1: P = W0;  Q = W1a;  break;
        case 2: P = W1b; Q = Wout; break;
        case 3: P = W0;  Q = W2a;  break;
        default: P = W2b; Q = Wout; break;
    }
    gemm64_f32(P, Q, dst + (size_t)blockIdx.z * 65536, blockIdx.x * 64, blockIdx.y * 64);
}

// transpose+convert 7 256x256 fp32 blocks -> bf16 [n][k]
__global__ __launch_bounds__(256) void transpose_all(
    const float* __restrict__ fw, const float* __restrict__ W1a,
    const float* __restrict__ W2a, u16* __restrict__ dstbase) {
    int z = blockIdx.y;
    const float* src = (z < 5) ? fw + (size_t)z * 65536
                               : (z == 5 ? W1a + 65536 : W2a + 65536);
    u16* dst = dstbase + (size_t)z * 65536;
    int t = blockIdx.x * 256 + threadIdx.x;  // 0..65535
    int i = t >> 8, j = t & 255;
    dst[(size_t)j * DD + i] = f2bf(src[(size_t)i * DD + j]);
}

// 5 fused bias vectors in one launch
__global__ void bias_all(const float* b0, const float* b1a, const float* b1b,
                         const float* b2a, const float* b2b, const float* bout,
                         const float* W1a, const float* W2a, const float* Wout,
                         float* BF) {
    int z = blockIdx.x, j = threadIdx.x;
    const float *b, *R, *add;
    switch (z) {
        case 0: b = b0;  R = Wout; add = bout; break;
        case 1: b = b0;  R = W1a;  add = b1a;  break;
        case 2: b = b1b; R = Wout; add = bout; break;
        case 3: b = b0;  R = W2a;  add = b2a;  break;
        default: b = b2b; R = Wout; add = bout; break;
    }
    float s = add[j];
    for (int k = 0; k < DD; ++k) s += b[k] * R[k * DD + j];
    BF[z * DD + j] = s;
}

// fp32 -> bf16 bulk convert (n4 float4 groups)
__global__ __launch_bounds__(256) void convert_bf16(const float* __restrict__ in,
                                                    u16* __restrict__ out, long n4) {
    long i = (long)blockIdx.x * 256 + threadIdx.x;
    long stride = (long)gridDim.x * 256;
    for (; i < n4; i += stride) {
        float4 v = ((const float4*)in)[i];
        ushort4 o = {f2bf(v.x), f2bf(v.y), f2bf(v.z), f2bf(v.w)};
        ((ushort4*)out)[i] = o;
    }
}

// masked mean gather, bf16 src -> bf16 out. blockDim (64,4).
__global__ __launch_bounds__(256) void gather_b(
    const u16* __restrict__ src, const int* __restrict__ idx,
    const float* __restrict__ mask, u16* __restrict__ out, int C, int K) {
    int c = blockIdx.x * 4 + threadIdx.y;
    if (c >= C) return;
    int t = threadIdx.x;  // 0..63, 4 bf16 each
    float a0 = 0, a1 = 0, a2 = 0, a3 = 0, cnt = 0;
    for (int k = 0; k < K; ++k) {
        float m = mask[(size_t)c * K + k];
        cnt += m;
        if (m != 0.f) {
            int r = idx[(size_t)c * K + k];
            ushort4 v = *(const ushort4*)&src[(size_t)r * DD + t * 4];
            a0 += m * bf2f(v.x); a1 += m * bf2f(v.y);
            a2 += m * bf2f(v.z); a3 += m * bf2f(v.w);
        }
    }
    float inv = (cnt > 0.f) ? 1.f / fmaxf(cnt, 1.f) : 0.f;
    ushort4 o = {f2bf(a0 * inv), f2bf(a1 * inv), f2bf(a2 * inv), f2bf(a3 * inv)};
    *(ushort4*)&out[(size_t)c * DD + t * 4] = o;
}

// masked mean gather, fp32 src -> bf16 out. blockDim (64,4).
__global__ __launch_bounds__(256) void gather_f(
    const float* __restrict__ src, const int* __restrict__ idx,
    const float* __restrict__ mask, u16* __restrict__ out, int C, int K) {
    int c = blockIdx.x * 4 + threadIdx.y;
    if (c >= C) return;
    int t = threadIdx.x;  // 0..63, 4 floats each
    float a0 = 0, a1 = 0, a2 = 0, a3 = 0, cnt = 0;
    for (int k = 0; k < K; ++k) {
        float m = mask[(size_t)c * K + k];
        cnt += m;
        if (m != 0.f) {
            int r = idx[(size_t)c * K + k];
            float4 v = *(const float4*)&src[(size_t)r * DD + t * 4];
            a0 += m * v.x; a1 += m * v.y; a2 += m * v.z; a3 += m * v.w;
        }
    }
    float inv = (cnt > 0.f) ? 1.f / fmaxf(cnt, 1.f) : 0.f;
    ushort4 o = {f2bf(a0 * inv), f2bf(a1 * inv), f2bf(a2 * inv), f2bf(a3 * inv)};
    *(ushort4*)&out[(size_t)c * DD + t * 4] = o;
}

// ---------------------------------------------------------------------------
// MFMA bf16 GEMM: C[M,256] = actA(A0)@B0 (+ A1p@B1) + bias
// B given TRANSPOSED bf16 [n][k] (256x256). 128x128 tile, 4 waves (2x2 of
// 64x64), BK=32, mfma_f32_16x16x32_bf16, global_load_lds w=16, XOR-swizzled
// LDS (s_p = s ^ ((row>>1)&3) on 16B slots -> 2-way bank access = free).
// ---------------------------------------------------------------------------
template<int TWO, int RELU_BF, int WF32, int WBF16>
__global__ __launch_bounds__(256) void gemm_mfma(
    const u16* __restrict__ A0, const u16* __restrict__ A1p,
    const u16* __restrict__ B0t, const u16* __restrict__ B1t,
    const float* __restrict__ bias, float* __restrict__ Cf,
    u16* __restrict__ Cb, int M) {
    __shared__ __align__(16) u16 As[4096];  // [128][32] bf16, swizzled
    __shared__ __align__(16) u16 Bs[4096];
    const int tid = threadIdx.x;
    const int wave = tid >> 6;
    const int lane = tid & 63;
    const int bm = blockIdx.x * 128;
    const int bn = blockIdx.y * 128;
    const int wr = wave >> 1, wc = wave & 1;

    // staging: 512 16B-slots per tile; thread handles slots p0=wave*64+lane,
    // p1 = p0+256. slot p -> LDS row p>>2, phys 16B-slot p&3; global col-slot
    // s = (p&3) ^ ((row>>1)&3)  (involution, applied again on read).
    const int p0 = wave * 64 + lane, p1 = p0 + 256;
    const int r0 = p0 >> 2, r1 = p1 >> 2;
    const int s0 = (p0 & 3) ^ ((r0 >> 1) & 3);
    const int s1 = (p1 & 3) ^ ((r1 >> 1) & 3);
    const size_t aoff0 = (size_t)min(bm + r0, M - 1) * DD + s0 * 8;
    const size_t aoff1 = (size_t)min(bm + r1, M - 1) * DD + s1 * 8;
    const size_t boff0 = (size_t)(bn + r0) * DD + s0 * 8;
    const size_t boff1 = (size_t)(bn + r1) * DD + s1 * 8;
    u16* AsW0 = As + wave * 512;          // chunk 0, wave-uniform base
    u16* AsW1 = As + 2048 + wave * 512;   // chunk 1
    u16* BsW0 = Bs + wave * 512;
    u16* BsW1 = Bs + 2048 + wave * 512;

    f32x4 acc[4][4] = {};

    const int ra = wr * 64 + (lane & 15);
    const int rb = wc * 64 + (lane & 15);
    const int sF = lane >> 4;

#define GLL(g, l) __builtin_amdgcn_global_load_lds( \
        (const __attribute__((address_space(1))) void*)(g), \
        (__attribute__((address_space(3))) void*)(l), 16, 0, 0)

    const int nparts = TWO ? 2 : 1;
    for (int part = 0; part < nparts; ++part) {
        const u16* __restrict__ A  = part ? A1p : A0;
        const u16* __restrict__ Bt = part ? B1t : B0t;
        for (int k0 = 0; k0 < DD; k0 += 32) {
            __syncthreads();  // previous iteration's LDS reads done
            GLL(A + aoff0 + k0, AsW0);
            GLL(A + aoff1 + k0, AsW1);
            GLL(Bt + boff0 + k0, BsW0);
            GLL(Bt + boff1 + k0, BsW1);
            __syncthreads();  // compiler drains vmcnt before s_barrier

            bf16x8 af[4], bfr[4];
#pragma unroll
            for (int mi = 0; mi < 4; ++mi) {
                int row = ra + mi * 16;
                int sp = sF ^ ((row >> 1) & 3);
                af[mi] = *(const bf16x8*)(As + row * 32 + sp * 8);
            }
#pragma unroll
            for (int ni = 0; ni < 4; ++ni) {
                int row = rb + ni * 16;
                int sp = sF ^ ((row >> 1) & 3);
                bfr[ni] = *(const bf16x8*)(Bs + row * 32 + sp * 8);
            }
#pragma unroll
            for (int mi = 0; mi < 4; ++mi)
#pragma unroll
                for (int ni = 0; ni < 4; ++ni)
                    acc[mi][ni] = __builtin_amdgcn_mfma_f32_16x16x32_bf16(
                        af[mi], bfr[ni], acc[mi][ni], 0, 0, 0);
        }
    }
#undef GLL

    // epilogue: C/D layout col=lane&15, row=(lane>>4)*4+reg
    const int col_l = bn + wc * 64 + (lane & 15);
    const int rbase = bm + wr * 64 + (lane >> 4) * 4;
#pragma unroll
    for (int mi = 0; mi < 4; ++mi) {
#pragma unroll
        for (int r = 0; r < 4; ++r) {
            int row = rbase + mi * 16 + r;
            if (row < M) {
#pragma unroll
                for (int ni = 0; ni < 4; ++ni) {
                    int col = col_l + ni * 16;
                    float v = acc[mi][ni][r] + bias[col];
                    if (WF32) Cf[(size_t)row * DD + col] = v;
                    if (WBF16) {
                        float vb = RELU_BF ? fmaxf(v, 0.f) : v;
                        Cb[(size_t)row * DD + col] = f2bf(vb);
                    }
                }
            }
        }
    }
}

extern "C" void kernel_launch(void* const* d_in, const int* in_sizes, int n_in,
                              void* d_out, int out_size, void* d_ws, size_t ws_size,
                              hipStream_t stream) {
    const float* X     = (const float*)d_in[0];
    const int*   d1_ci = (const int*)d_in[1];
    const int*   d1_bi = (const int*)d_in[2];
    const int*   d2_ci = (const int*)d_in[3];
    const int*   d2_bi = (const int*)d_in[4];
    const float* d1_cm = (const float*)d_in[5];
    const float* d1_bm = (const float*)d_in[6];
    const float* d2_cm = (const float*)d_in[7];
    const float* d2_bm = (const float*)d_in[8];
    const float* W0   = (const float*)d_in[9];
    const float* b0   = (const float*)d_in[10];
    const float* W1a  = (const float*)d_in[11];
    const float* b1a  = (const float*)d_in[12];
    const float* W1b  = (const float*)d_in[13];
    const float* b1b  = (const float*)d_in[14];
    const float* W2a  = (const float*)d_in[15];
    const float* b2a  = (const float*)d_in[16];
    const float* W2b  = (const float*)d_in[17];
    const float* b2b  = (const float*)d_in[18];
    const float* Wout = (const float*)d_in[19];
    const float* bout = (const float*)d_in[20];

    const int N  = in_sizes[0] / DD;   // 100000
    const int C1 = in_sizes[1] / 16;   // 50000
    const int C2 = in_sizes[3] / 32;   // 10000

    float* out  = (float*)d_out;
    float* emb0 = out;
    float* emb1 = out + (size_t)N * DD;
    float* emb2 = out + (size_t)(N + C1) * DD;

    // ---- workspace layout (~130 MB) ----
    u16* Xb  = (u16*)d_ws;                     // [N,256] bf16
    u16* A1b = Xb  + (size_t)N * DD;           // [C1,256]
    u16* B1b = A1b + (size_t)C1 * DD;          // [C1,256]
    u16* H1b = B1b + (size_t)C1 * DD;          // [C1,256]
    u16* WT  = H1b + (size_t)C1 * DD;          // 7 x 256x256 bf16 transposed
    float* FW = (float*)(((uintptr_t)(WT + 7 * 65536) + 15) & ~(uintptr_t)15);
    float* BF = FW + 5 * 65536;                // 5 x 256 fused biases
    // dim-2 buffers reuse A1b region (dead after emb1 GEMM)
    u16* A2b = A1b;
    u16* B2b = A1b + (size_t)C2 * DD;
    u16* H2b = A1b + (size_t)2 * C2 * DD;

    u16* Wf_t   = WT;
    u16* U1_t   = WT + 1 * 65536;
    u16* V1_t   = WT + 2 * 65536;
    u16* U2_t   = WT + 3 * 65536;
    u16* V2_t   = WT + 4 * 65536;
    u16* W1ab_t = WT + 5 * 65536;
    u16* W2ab_t = WT + 6 * 65536;

    // ---- weight prep ----
    fuse_weights<<<dim3(4, 4, 5), 256, 0, stream>>>(W0, W1a, W1b, W2a, W2b, Wout, FW);
    transpose_all<<<dim3(256, 7), 256, 0, stream>>>(FW, W1a, W2a, WT);
    bias_all<<<5, 256, 0, stream>>>(b0, b1a, b1b, b2a, b2b, bout, W1a, W2a, Wout, BF);
    convert_bf16<<<2048, 256, 0, stream>>>(X, Xb, (long)N * 64);

    dim3 tb(256);
    // ---- dim 0: emb0 = Xb @ Wf + bf ----
    gemm_mfma<0, 0, 1, 0><<<dim3((N + 127) / 128, 2), tb, 0, stream>>>(
        Xb, nullptr, Wf_t, nullptr, BF + 0, emb0, nullptr, N);

    // ---- dim 1 ----
    gather_b<<<dim3((C1 + 3) / 4), dim3(64, 4), 0, stream>>>(Xb,   d1_ci, d1_cm, A1b, C1, 16);
    gather_f<<<dim3((C1 + 3) / 4), dim3(64, 4), 0, stream>>>(emb0, d1_bi, d1_bm, B1b, C1, 16);
    gemm_mfma<1, 1, 0, 1><<<dim3((C1 + 127) / 128, 2), tb, 0, stream>>>(
        A1b, B1b, U1_t, W1ab_t, BF + 256, nullptr, H1b, C1);
    gemm_mfma<0, 0, 1, 0><<<dim3((C1 + 127) / 128, 2), tb, 0, stream>>>(
        H1b, nullptr, V1_t, nullptr, BF + 512, emb1, nullptr, C1);

    // ---- dim 2 ----
    gather_b<<<dim3((C2 + 3) / 4), dim3(64, 4), 0, stream>>>(Xb,   d2_ci, d2_cm, A2b, C2, 32);
    gather_f<<<dim3((C2 + 3) / 4), dim3(64, 4), 0, stream>>>(emb1, d2_bi, d2_bm, B2b, C2, 8);
    gemm_mfma<1, 1, 0, 1><<<dim3((C2 + 127) / 128, 2), tb, 0, stream>>>(
        A2b, B2b, U2_t, W2ab_t, BF + 768, nullptr, H2b, C2);
    gemm_mfma<0, 0, 1, 0><<<dim3((C2 + 127) / 128, 2), tb, 0, stream>>>(
        H2b, nullptr, V2_t, nullptr, BF + 1024, emb2, nullptr, C2);
}